// Round 4
// baseline (309.420 us; speedup 1.0000x reference)
//
#include <hip/hip_runtime.h>
#include <hip/hip_bf16.h>

#define NGRAPH 1024
#define NPG 128
#define EPG 2048
#define ETOT (NGRAPH*NPG*16)
#define HD 64

typedef unsigned int uint;
typedef unsigned short ushort_t;
typedef __attribute__((ext_vector_type(8))) short s8v;
typedef __attribute__((ext_vector_type(4))) float f32x4;

#define MFMA16 __builtin_amdgcn_mfma_f32_16x16x32_bf16

__device__ __forceinline__ float lrelu(float x, float s){ return fmaxf(x, x*s); }
__device__ __forceinline__ float b2lo(uint u){ return __uint_as_float(u << 16); }
__device__ __forceinline__ float b2hi(uint u){ return __uint_as_float(u & 0xFFFF0000u); }
__device__ __forceinline__ uint pkbf(float a, float b){
  union { __hip_bfloat162 h; uint u; } t;
  t.h = __hip_bfloat162{__float2bfloat16(a), __float2bfloat16(b)};
  return t.u;
}
__device__ __forceinline__ ushort_t bfb(float v){
  union { __hip_bfloat16 h; ushort_t u; } t; t.h = __float2bfloat16(v); return t.u;
}
union U4S8 { uint4 u; s8v s; };
__device__ __forceinline__ s8v bcs8(uint4 u){ U4S8 t; t.u = u; return t.s; }
__device__ __forceinline__ s8v pk8(uint4 x, uint4 y){
  U4S8 t;
  t.u.x = pkbf(__uint_as_float(x.x), __uint_as_float(x.y));
  t.u.y = pkbf(__uint_as_float(x.z), __uint_as_float(x.w));
  t.u.z = pkbf(__uint_as_float(y.x), __uint_as_float(y.y));
  t.u.w = pkbf(__uint_as_float(y.z), __uint_as_float(y.w));
  return t.s;
}
#define DPP_ADD(v, ctrl) ((v) + __int_as_float(__builtin_amdgcn_update_dpp(0, __float_as_int(v), (ctrl), 0xF, 0xF, false)))

// bf16 rows of 64 (32 u32 pairs), octet-XOR swizzle
__device__ __forceinline__ int oswz(int r, int p){ return (r<<5) | ((((p>>2) ^ (r & 7))<<2) | (p & 3)); }
__device__ __forceinline__ int obase(int r, int oc){ return (r<<5) | (((oc) ^ (r & 7))<<2); }
// bf16 rows of 128 (64 u32 pairs), 16-row-XOR swizzle
__device__ __forceinline__ int t64(int r, int p){ return (r<<6) | ((((p>>2) ^ (r & 15))<<2) | (p & 3)); }
__device__ __forceinline__ int t64b(int r, int q){ return (r<<6) | (((q ^ (r & 15))<<2)); }
// f32 P [16][128], row-XOR quad swizzle
__device__ __forceinline__ int fP16(int r, int k){ return (r<<7) | (((((k>>2) ^ r) & 31)<<2) | (k & 3)); }
__device__ __forceinline__ int fP16b(int r, int q){ return (r<<7) | ((((q ^ r) & 31))<<2); }

// LDS map (u32 words) — total 12609 w = 50436 B -> 3 blocks/CU
#define O_H   0        // 4096: xl -> h (sH)  ROW32 [128][32]
#define O_T   4096     // 4096: xr -> xlT / XwT
#define O_P   8192     // 2048: P f32 [16][128]; aliases: edsd-stage u16[2048](=1024w)+spos[128]; was[64]+wad[64]
#define O_E   10240    // 2048: eva f32 [2048] / WgT bf16 [64][32]
#define O_SOF 12288    // soff u16[130] = 65 w
#define O_ALS 12353    // 128: als / self-weights
#define O_ALD 12481    // 128: ald
#define SM_SZ 12609

__device__ __forceinline__ void aggregate_rounds(
    uint* SM, const ushort_t* soff16, const float* eva, const ushort_t* edsG,
    const float* selfw, const float* biasp, bool dorelu,
    int tid, int wv, int lw, int lq)
{
  float* Pf = (float*)(SM + O_P);
  ushort_t* sH16 = (ushort_t*)(SM + O_H);
  float bj = biasp[16*wv + lw];
  for (int q = 0; q < 8; q++) {
    // zero P
    uint4 z = {0,0,0,0};
    *(uint4*)&SM[O_P + tid*8]     = z;
    *(uint4*)&SM[O_P + tid*8 + 4] = z;
    __syncthreads();
    // scatter normalized attention weights
    int p0 = soff16[q*16], p1 = soff16[q*16 + 16];
    for (int p = p0 + tid; p < p1; p += 256) {
      int sd = edsG[p];
      atomicAdd(&Pf[fP16((sd >> 8) - q*16, sd & 127)], eva[p]);
    }
    if (selfw && tid < 16)
      atomicAdd(&Pf[fP16(tid, q*16 + tid)], selfw[q*16 + tid]);
    __syncthreads();
    // out[16 dst][64 feat] = P @ XwT^T via MFMA; wave -> feature tile
    f32x4 c = {0.f,0.f,0.f,0.f};
    #pragma unroll
    for (int ks = 0; ks < 4; ks++) {
      int kk = ks*32 + lq*8;
      uint4 f0 = *(uint4*)&Pf[fP16b(lw, (kk>>2))];
      uint4 f1 = *(uint4*)&Pf[fP16b(lw, (kk>>2)+1)];
      s8v a = pk8(f0, f1);
      s8v b = bcs8(*(uint4*)&SM[O_T + t64b(16*wv + lw, kk>>3)]);
      c = MFMA16(a, b, c, 0, 0, 0);
    }
    int col = 16*wv + lw;
    #pragma unroll
    for (int rg = 0; rg < 4; rg++) {
      float v = c[rg] + bj;
      v = dorelu ? fmaxf(v, 0.f) : lrelu(v, 0.01f);
      int r = q*16 + lq*4 + rg;
      sH16[oswz(r, col>>1)*2 + (col&1)] = bfb(v);
    }
    __syncthreads();
  }
}

__global__ __launch_bounds__(256, 3) void gnn_fused(
    const float* __restrict__ x, const int* __restrict__ ei,
    const float* __restrict__ Wl, const float* __restrict__ bl,
    const float* __restrict__ Wr, const float* __restrict__ br,
    const float* __restrict__ att, const float* __restrict__ bv2,
    const float* __restrict__ Wg1, const float* __restrict__ as1,
    const float* __restrict__ ad1, const float* __restrict__ bg1,
    const float* __restrict__ Wg2, const float* __restrict__ as2,
    const float* __restrict__ ad2, const float* __restrict__ bg2,
    const float* __restrict__ lng, const float* __restrict__ lnb,
    uint* __restrict__ hout, uint* __restrict__ edsd_ws)
{
  __shared__ uint SM[SM_SZ];
  float*    eva   = (float*)(SM + O_E);
  ushort_t* soff16= (ushort_t*)(SM + O_SOF);
  float*    als   = (float*)(SM + O_ALS);
  float*    ald   = (float*)(SM + O_ALD);
  ushort_t* sH16  = (ushort_t*)(SM + O_H);
  ushort_t* sT16  = (ushort_t*)(SM + O_T);

  const int g    = blockIdx.x;
  const int tid  = threadIdx.x;
  const int lane = tid & 63;
  const int wv   = tid >> 6;
  const int lw   = lane & 15;
  const int lq   = lane >> 4;
  const int oc   = lane & 7;
  const int ebase = g * EPG;
  uint* eg = edsd_ws + (size_t)g * 1024;            // 2048 u16 per graph
  const ushort_t* edsG = (const ushort_t*)eg;

  // ---------------- CSR build (stage in P region) ----------------
  {
    int* spos = (int*)(SM + O_P + 1024);
    ushort_t* edsL = (ushort_t*)(SM + O_P);
    if (tid < NPG) spos[tid] = 0;
    __syncthreads();
    for (int e = tid; e < EPG; e += 256)
      atomicAdd(&spos[ei[ETOT + ebase + e] - g*NPG], 1);
    __syncthreads();
    if (wv == 0) {
      int c0 = spos[lane], c1 = spos[lane + 64];
      #pragma unroll
      for (int o = 1; o < 64; o <<= 1) { int t = __shfl_up(c0, o); if (lane >= o) c0 += t; }
      #pragma unroll
      for (int o = 1; o < 64; o <<= 1) { int t = __shfl_up(c1, o); if (lane >= o) c1 += t; }
      int tot0 = __shfl(c0, 63);
      soff16[lane + 1]  = (ushort_t)c0;
      soff16[lane + 65] = (ushort_t)(c1 + tot0);
      if (lane == 0) soff16[0] = 0;
    }
    __syncthreads();
    if (tid < NPG) spos[tid] = soff16[tid];
    __syncthreads();
    for (int e = tid; e < EPG; e += 256) {
      int s = ei[ebase + e] - g*NPG;
      int d = ei[ETOT + ebase + e] - g*NPG;
      int p = atomicAdd(&spos[d], 1);
      edsL[p] = (ushort_t)(s | (d << 8));
    }
    __syncthreads();
  }

  // ---------------- copy edsd to ws + GATv2 transforms ----------------
  {
    #pragma unroll
    for (int i = 0; i < 4; i++) eg[tid + i*256] = SM[O_P + tid + i*256];

    const int pl = lane & 31, hb = lane >> 5;
    const float2 wl0 = *(const float2*)&Wl[0*64 + 2*pl];
    const float2 wl1 = *(const float2*)&Wl[1*64 + 2*pl];
    const float2 wl2 = *(const float2*)&Wl[2*64 + 2*pl];
    const float2 wl3 = *(const float2*)&Wl[3*64 + 2*pl];
    const float2 wr0 = *(const float2*)&Wr[0*64 + 2*pl];
    const float2 wr1 = *(const float2*)&Wr[1*64 + 2*pl];
    const float2 wr2 = *(const float2*)&Wr[2*64 + 2*pl];
    const float2 wr3 = *(const float2*)&Wr[3*64 + 2*pl];
    const float2 blp = *(const float2*)&bl[2*pl];
    const float2 brp = *(const float2*)&br[2*pl];
    const float4* x4 = (const float4*)x + (size_t)g * NPG;
    for (int st = 0; st < 16; st++) {
      int i = st*8 + wv*2 + hb;
      float4 xi = x4[i];
      float l0 = blp.x + xi.x*wl0.x + xi.y*wl1.x + xi.z*wl2.x + xi.w*wl3.x;
      float l1 = blp.y + xi.x*wl0.y + xi.y*wl1.y + xi.z*wl2.y + xi.w*wl3.y;
      float r0 = brp.x + xi.x*wr0.x + xi.y*wr1.x + xi.z*wr2.x + xi.w*wr3.x;
      float r1 = brp.y + xi.x*wr0.y + xi.y*wr1.y + xi.z*wr2.y + xi.w*wr3.y;
      SM[O_H + oswz(i, pl)] = pkbf(l0, l1);   // xl
      SM[O_T + oswz(i, pl)] = pkbf(r0, r1);   // xr
    }
  }
  __syncthreads();

  // ---------------- GATv2 edge logits (edsd still staged in P) ----------------
  {
    const int grp = lane >> 3;
    const ushort_t* edsL = (const ushort_t*)(SM + O_P);
    float4 atA = *(const float4*)&att[oc*8];
    float4 atB = *(const float4*)&att[oc*8 + 4];
    int base = wv * 512;
    for (int stp = 0; stp < 64; stp++) {
      int e  = base + stp*8 + grp;
      int sd = edsL[e];
      int s  = sd & 127, d = sd >> 8;
      uint4 ql = *(uint4*)&SM[O_H + obase(s, oc)];
      uint4 qr = *(uint4*)&SM[O_T + obase(d, oc)];
      float acc, v;
      v = b2lo(ql.x)+b2lo(qr.x); acc  = lrelu(v,0.2f)*atA.x;
      v = b2hi(ql.x)+b2hi(qr.x); acc += lrelu(v,0.2f)*atA.y;
      v = b2lo(ql.y)+b2lo(qr.y); acc += lrelu(v,0.2f)*atA.z;
      v = b2hi(ql.y)+b2hi(qr.y); acc += lrelu(v,0.2f)*atA.w;
      v = b2lo(ql.z)+b2lo(qr.z); acc += lrelu(v,0.2f)*atB.x;
      v = b2hi(ql.z)+b2hi(qr.z); acc += lrelu(v,0.2f)*atB.y;
      v = b2lo(ql.w)+b2lo(qr.w); acc += lrelu(v,0.2f)*atB.z;
      v = b2hi(ql.w)+b2hi(qr.w); acc += lrelu(v,0.2f)*atB.w;
      acc = DPP_ADD(acc, 0x111); acc = DPP_ADD(acc, 0x112); acc = DPP_ADD(acc, 0x114);
      if ((lane & 7) == 7) eva[e] = acc;
    }
  }
  __syncthreads();

  // ---------------- GATv2 softmax (normalized in place) + xl -> xlT ----------------
  {
    const int g16 = tid >> 4, sl = tid & 15;
    for (int it = 0; it < 8; it++) {
      int d = it*16 + g16;
      int p0 = soff16[d], p1 = soff16[d+1];
      float m = -1e30f;
      for (int p = p0 + sl; p < p1; p += 16) m = fmaxf(m, eva[p]);
      #pragma unroll
      for (int o = 1; o < 16; o <<= 1) m = fmaxf(m, __shfl_xor(m, o));
      float ssum = 0.f;
      for (int p = p0 + sl; p < p1; p += 16) { float ex = __expf(eva[p]-m); ssum += ex; eva[p] = ex; }
      #pragma unroll
      for (int o = 1; o < 16; o <<= 1) ssum += __shfl_xor(ssum, o);
      float rnm = 1.f / (ssum + 1e-16f);
      for (int p = p0 + sl; p < p1; p += 16) eva[p] *= rnm;
    }
    // transpose xl (ROW32 [s][j]) -> xlT (ROW64 [j][s]) over dead xr
    ushort_t* xl16 = (ushort_t*)(SM + O_H);
    int j = tid & 63, spb = tid >> 6;
    for (int i = 0; i < 16; i++) {
      int sp = spb*16 + i;
      float v0 = __uint_as_float((uint)xl16[oswz(2*sp,   j>>1)*2 + (j&1)] << 16);
      float v1 = __uint_as_float((uint)xl16[oswz(2*sp+1, j>>1)*2 + (j&1)] << 16);
      SM[O_T + t64(j, sp)] = pkbf(v0, v1);
    }
  }
  __syncthreads();

  // ---------------- GATv2 aggregate (no self), bias + leaky 0.01 ----------------
  aggregate_rounds(SM, soff16, eva, edsG, nullptr, bv2, false, tid, wv, lw, lq);

  // ---------------- LayerNorm in place on sH (bf16) ----------------
  {
    int pl = lane & 31, hb = lane >> 5;
    float2 gv = *(const float2*)&lng[2*pl];
    float2 bv = *(const float2*)&lnb[2*pl];
    for (int it = 0; it < 16; it++) {
      int d = it*8 + wv*2 + hb;
      uint w = SM[O_H + oswz(d, pl)];
      float v0 = b2lo(w), v1 = b2hi(w);
      float s1 = v0 + v1, s2 = v0*v0 + v1*v1;
      #pragma unroll
      for (int o = 1; o < 32; o <<= 1) { s1 += __shfl_xor(s1, o); s2 += __shfl_xor(s2, o); }
      float mu  = s1 * 0.015625f;
      float var = s2 * 0.015625f - mu*mu;
      float rs  = rsqrtf(var + 1e-5f);
      SM[O_H + oswz(d, pl)] = pkbf((v0-mu)*rs*gv.x + bv.x, (v1-mu)*rs*gv.y + bv.y);
    }
  }
  __syncthreads();

  // ---------------- two GATConv layers ----------------
  for (int layer = 0; layer < 2; layer++) {
    const float* Wg  = layer ? Wg2 : Wg1;
    const float* avs = layer ? as2 : as1;
    const float* avd = layer ? ad2 : ad1;
    const float* bg  = layer ? bg2 : bg1;
    float* was = (float*)(SM + O_P);        // P dead until rounds
    float* wad = was + 64;
    ushort_t* wg16 = (ushort_t*)(SM + O_E); // eva dead until logits

    // stage: was/wad = Wg @ a ; WgT bf16
    if (tid < 128) {
      const float* av = (tid < 64) ? avs : avd;
      float* dst = (tid < 64) ? was : wad;
      int k = tid & 63;
      float acc = 0.f;
      #pragma unroll
      for (int jj = 0; jj < 16; jj++) {
        float4 w = *(const float4*)&Wg[k*64 + jj*4];
        float4 a = *(const float4*)&av[jj*4];
        acc += w.x*a.x + w.y*a.y + w.z*a.z + w.w*a.w;
      }
      dst[k] = acc;
    } else {
      int t2 = tid - 128;
      #pragma unroll
      for (int i = 0; i < 8; i++) {
        int idx = t2 + i*128;
        int k = idx >> 4, j4 = (idx & 15)*4;
        float4 w = *(const float4*)&Wg[k*64 + j4];
        wg16[oswz(j4+0, k>>1)*2 + (k&1)] = bfb(w.x);
        wg16[oswz(j4+1, k>>1)*2 + (k&1)] = bfb(w.y);
        wg16[oswz(j4+2, k>>1)*2 + (k&1)] = bfb(w.z);
        wg16[oswz(j4+3, k>>1)*2 + (k&1)] = bfb(w.w);
      }
    }
    __syncthreads();

    // transform MFMA: XwT[j][d] = (h @ Wg)^T
    {
      int row = 16*wv + lw;
      s8v a0 = bcs8(*(uint4*)&SM[O_E + obase(row, lq)]);
      s8v a1 = bcs8(*(uint4*)&SM[O_E + obase(row, 4+lq)]);
      #pragma unroll
      for (int nt = 0; nt < 8; nt++) {
        int d = nt*16 + lw;
        s8v b0 = bcs8(*(uint4*)&SM[O_H + obase(d, lq)]);
        s8v b1 = bcs8(*(uint4*)&SM[O_H + obase(d, 4+lq)]);
        f32x4 c = {0.f,0.f,0.f,0.f};
        c = MFMA16(a0, b0, c, 0, 0, 0);
        c = MFMA16(a1, b1, c, 0, 0, 0);
        int j0 = 16*wv + lq*4;
        #pragma unroll
        for (int rg = 0; rg < 4; rg++)
          sT16[t64(j0+rg, d>>1)*2 + (d&1)] = bfb(c[rg]);
      }
    }
    __syncthreads();

    // als/ald = h @ wa (8-lane groups, DPP reduce)
    {
      float4 ws0 = *(float4*)&was[oc*8], ws1 = *(float4*)&was[oc*8 + 4];
      float4 wd0 = *(float4*)&wad[oc*8], wd1 = *(float4*)&wad[oc*8 + 4];
      for (int ps = 0; ps < 4; ps++) {
        int n = ps*32 + (tid >> 3);
        uint4 q = *(uint4*)&SM[O_H + obase(n, oc)];
        float f0=b2lo(q.x), f1=b2hi(q.x), f2=b2lo(q.y), f3=b2hi(q.y);
        float f4=b2lo(q.z), f5=b2hi(q.z), f6=b2lo(q.w), f7=b2hi(q.w);
        float sa = f0*ws0.x+f1*ws0.y+f2*ws0.z+f3*ws0.w+f4*ws1.x+f5*ws1.y+f6*ws1.z+f7*ws1.w;
        float sd = f0*wd0.x+f1*wd0.y+f2*wd0.z+f3*wd0.w+f4*wd1.x+f5*wd1.y+f6*wd1.z+f7*wd1.w;
        sa = DPP_ADD(sa, 0x111); sa = DPP_ADD(sa, 0x112); sa = DPP_ADD(sa, 0x114);
        sd = DPP_ADD(sd, 0x111); sd = DPP_ADD(sd, 0x112); sd = DPP_ADD(sd, 0x114);
        if ((lane & 7) == 7) { als[n] = sa; ald[n] = sd; }
      }
    }
    __syncthreads();

    // edge logits (rank-1), edsd from ws (L1-hot)
    #pragma unroll
    for (int i = 0; i < 4; i++) {
      uint w = eg[tid + i*256];
      int e = (tid + i*256)*2;
      int sd0 = w & 0xFFFF, sd1 = w >> 16;
      eva[e]   = lrelu(als[sd0 & 127] + ald[sd0 >> 8], 0.2f);
      eva[e+1] = lrelu(als[sd1 & 127] + ald[sd1 >> 8], 0.2f);
    }
    __syncthreads();

    // softmax incl self-loop; normalized in place; self-weight -> als
    {
      const int g16 = tid >> 4, sl = tid & 15;
      for (int it = 0; it < 8; it++) {
        int d = it*16 + g16;
        int p0 = soff16[d], p1 = soff16[d+1];
        float se = lrelu(als[d] + ald[d], 0.2f);
        float m = se;
        for (int p = p0 + sl; p < p1; p += 16) m = fmaxf(m, eva[p]);
        #pragma unroll
        for (int o = 1; o < 16; o <<= 1) m = fmaxf(m, __shfl_xor(m, o));
        float ex0 = __expf(se - m);
        float ssum = 0.f;
        for (int p = p0 + sl; p < p1; p += 16) { float ex = __expf(eva[p]-m); ssum += ex; eva[p] = ex; }
        #pragma unroll
        for (int o = 1; o < 16; o <<= 1) ssum += __shfl_xor(ssum, o);
        float rnm = 1.f / (ssum + ex0 + 1e-16f);
        for (int p = p0 + sl; p < p1; p += 16) eva[p] *= rnm;
        if (sl == 0) als[d] = ex0 * rnm;
      }
    }
    __syncthreads();

    // aggregate incl self, bias + relu
    aggregate_rounds(SM, soff16, eva, edsG, als, bg, true, tid, wv, lw, lq);
  }

  // ---------------- write h (bf16 pairs, node-major) ----------------
  {
    uint* hg = hout + (size_t)g * 4096;
    #pragma unroll
    for (int i = 0; i < 16; i++) {
      int idx = tid + i*256;
      hg[idx] = SM[O_H + oswz(idx >> 5, idx & 31)];
    }
  }
}

// ---------------- W1 -> W1T bf16 pair transpose ----------------
__global__ __launch_bounds__(256) void w1_transpose(const float* __restrict__ W1,
                                                    uint* __restrict__ w1t)
{
  __shared__ float sw[64*130];
  const int tid = threadIdx.x;
  const int k0 = blockIdx.x * 64;
  #pragma unroll
  for (int i = 0; i < 8; i++) {
    int idx = tid + i*256;
    int r = idx >> 5, c4 = (idx & 31)*4;
    *(float4*)&sw[r*130 + c4] = *(const float4*)&W1[(size_t)(k0+r)*128 + c4];
  }
  __syncthreads();
  #pragma unroll
  for (int i = 0; i < 16; i++) {
    int idx = tid + i*256;
    int c = idx >> 5, kp = idx & 31;
    w1t[(size_t)c*4096 + (k0>>1) + kp] = pkbf(sw[(2*kp)*130 + c], sw[(2*kp+1)*130 + c]);
  }
}

// ---------------- head GEMM: MFMA, split-K 16 ----------------
__global__ __launch_bounds__(256) void head_gemm(
    const uint* __restrict__ hbuf, const uint* __restrict__ w1t,
    float* __restrict__ partial)
{
  __shared__ uint sAh[2048];
  __shared__ uint sBh[4096];
  const int tid = threadIdx.x, lane = tid & 63, wv = tid >> 6;
  const int lw = lane & 15, lq = lane >> 4;
  const int g0 = blockIdx.x * 64;
  const int ks = blockIdx.y;
  f32x4 acc[8];
  #pragma unroll
  for (int i = 0; i < 8; i++) acc[i] = f32x4{0.f,0.f,0.f,0.f};

  for (int ch = 0; ch < 8; ch++) {
    int pb = ks*256 + ch*32;
    #pragma unroll
    for (int i = 0; i < 2; i++) {
      int idx = tid + i*256; int r = idx >> 3, q4 = idx & 7;
      uint4 v = *(const uint4*)&hbuf[(size_t)(g0+r)*4096 + pb + q4*4];
      *(uint4*)&sAh[(r<<5) | ((q4 ^ (r & 7))<<2)] = v;
    }
    #pragma unroll
    for (int i = 0; i < 4; i++) {
      int idx = tid + i*256; int r = idx >> 3, q4 = idx & 7;
      uint4 v = *(const uint4*)&w1t[(size_t)r*4096 + pb + q4*4];
      *(uint4*)&sBh[(r<<5) | ((q4 ^ (r & 7))<<2)] = v;
    }
    __syncthreads();
    int ra = 16*wv + lw;
    s8v a0 = bcs8(*(uint4*)&sAh[obase(ra, lq)]);
    s8v a1 = bcs8(*(uint4*)&sAh[obase(ra, 4+lq)]);
    #pragma unroll
    for (int nt = 0; nt < 8; nt++) {
      int c = nt*16 + lw;
      s8v b0 = bcs8(*(uint4*)&sBh[obase(c, lq)]);
      s8v b1 = bcs8(*(uint4*)&sBh[obase(c, 4+lq)]);
      acc[nt] = MFMA16(a0, b0, acc[nt], 0, 0, 0);
      acc[nt] = MFMA16(a1, b1, acc[nt], 0, 0, 0);
    }
    __syncthreads();
  }
  float* pp = partial + (size_t)ks*131072;
  #pragma unroll
  for (int nt = 0; nt < 8; nt++) {
    int c = nt*16 + lw;
    int r0 = g0 + 16*wv + lq*4;
    #pragma unroll
    for (int rg = 0; rg < 4; rg++)
      pp[(size_t)(r0+rg)*128 + c] = acc[nt][rg];
  }
}

// ---------------- head epilogue ----------------
__global__ __launch_bounds__(64) void head_out(
    const float* __restrict__ partial, const float* __restrict__ b1,
    const float* __restrict__ W2, const float* __restrict__ b2,
    float* __restrict__ out)
{
  const int g = blockIdx.x;
  const int l = threadIdx.x;
  float v0 = b1[l], v1 = b1[64 + l];
  #pragma unroll
  for (int s = 0; s < 16; s++) {
    v0 += partial[(size_t)s*131072 + g*128 + l];
    v1 += partial[(size_t)s*131072 + g*128 + 64 + l];
  }
  float sum = lrelu(v0, 0.01f)*W2[l] + lrelu(v1, 0.01f)*W2[64 + l];
  #pragma unroll
  for (int m = 32; m > 0; m >>= 1) sum += __shfl_xor(sum, m);
  if (l == 0) out[g] = 1.f / (1.f + __expf(-(sum + b2[0])));
}

extern "C" void kernel_launch(void* const* d_in, const int* in_sizes, int n_in,
                              void* d_out, int out_size, void* d_ws, size_t ws_size,
                              hipStream_t stream) {
  const float* x   = (const float*)d_in[0];
  const int*   ei  = (const int*)  d_in[1];
  const float* Wl  = (const float*)d_in[2];
  const float* bl_ = (const float*)d_in[3];
  const float* Wr  = (const float*)d_in[4];
  const float* br_ = (const float*)d_in[5];
  const float* att = (const float*)d_in[6];
  const float* bv2 = (const float*)d_in[7];
  const float* Wg1 = (const float*)d_in[8];
  const float* as1 = (const float*)d_in[9];
  const float* ad1 = (const float*)d_in[10];
  const float* bg1 = (const float*)d_in[11];
  const float* Wg2 = (const float*)d_in[12];
  const float* as2 = (const float*)d_in[13];
  const float* ad2 = (const float*)d_in[14];
  const float* bg2 = (const float*)d_in[15];
  const float* lng = (const float*)d_in[16];
  const float* lnb = (const float*)d_in[17];
  const float* W1  = (const float*)d_in[18];
  const float* b1  = (const float*)d_in[19];
  const float* W2  = (const float*)d_in[20];
  const float* b2  = (const float*)d_in[21];
  float* out = (float*)d_out;

  uint*  hbuf    = (uint*)d_ws;                                      // 16 MB
  float* partial = (float*)((char*)d_ws + (size_t)16*1024*1024);     // 8 MB
  uint*  w1t     = (uint*)((char*)d_ws + (size_t)24*1024*1024);      // 2 MB
  uint*  edsd_ws = (uint*)((char*)d_ws + (size_t)26*1024*1024);      // 4 MB

  w1_transpose<<<128, 256, 0, stream>>>(W1, w1t);
  gnn_fused<<<NGRAPH, 256, 0, stream>>>(x, ei, Wl, bl_, Wr, br_, att, bv2,
      Wg1, as1, ad1, bg1, Wg2, as2, ad2, bg2, lng, lnb, hbuf, edsd_ws);
  head_gemm<<<dim3(16, 16), 256, 0, stream>>>(hbuf, w1t, partial);
  head_out<<<NGRAPH, 64, 0, stream>>>(partial, b1, W2, b2, out);
}